// Round 8
// baseline (156.621 us; speedup 1.0000x reference)
//
#include <hip/hip_runtime.h>
#include <hip/hip_fp16.h>

// Problem constants (from reference).
#define N_GENOMES 30000
#define N_GENES   240000
#define N_SAMPLES 128
#define N_SEQS    80000
#define CAP       32    // max genes per seq (Poisson mean 3; realized max ~15)

// Static genome-order bins: bin = first_gene >> 5. A 32-gene window can
// produce at most 32 first-touch (slot-0) genes, so CAP2=32 is a HARD bound.
#define BIN_SHIFT 5
#define NBIN2     (N_GENES >> BIN_SHIFT)   // 7500
#define CAP2      32

#define SCATTER_BLOCKS  ((N_GENES + 255) / 256)        // 938
#define COMPRESS_BLOCKS ((N_GENOMES * 32) / 256)       // 3750 (exact)
#define SLOT_BLOCKS     (NBIN2 * CAP2 * 32 / 256)      // 30000 accum wave-slot blocks
#define EMPTY_BLOCKS    ((N_SEQS + 255) / 256)         // 313 zero-empty blocks

// Native vector types for __builtin_nontemporal_load/store.
typedef float        f32x4 __attribute__((ext_vector_type(4)));
typedef unsigned int u32x4 __attribute__((ext_vector_type(4)));

// ---------------------------------------------------------------------------
// Fused prep kernel.
// Blocks [0, SCATTER_BLOCKS): bucket-scatter genes by seq id with PACKED 4B
//   records: genome (15 bits) | pos quantized to 17 bits (exact pow2 scale).
//   The slot-0 gene of each seq ALSO registers the seq into a genome-ordered
//   2-D order table: order2D[first_gene>>5][atomic slot]. Since genome_idx is
//   sorted over genes, bin order == genome order.
// Blocks [SCATTER_BLOCKS, ...): compress A/B to fp16 interleaved per quad:
//   {a+1 x4, b x4} = 16B per (genome, quad); nontemporal A/B reads.
// ---------------------------------------------------------------------------
__global__ __launch_bounds__(256) void prep_kernel(
    const float* __restrict__ A,
    const float* __restrict__ B,
    const float* __restrict__ pos,
    const int*   __restrict__ genome_idx,
    const int*   __restrict__ seq_idx,
    int*          __restrict__ cnt,     // N_SEQS, zeroed
    int*          __restrict__ bincnt,  // NBIN2, zeroed
    unsigned int* __restrict__ bucket,  // N_SEQS * CAP packed records, zeroed
    int*          __restrict__ order2D, // NBIN2 * CAP2 (live entries only read)
    float4*       __restrict__ AB16)    // N_GENOMES*32 x 16B interleaved fp16
{
    int b = blockIdx.x;
    if (b < SCATTER_BLOCKS) {
        int gene = b * 256 + threadIdx.x;
        if (gene >= N_GENES) return;
        int   s = seq_idx[gene];
        int   g = genome_idx[gene];
        float p = pos[gene];
        unsigned int q   = (unsigned int)(p * 131072.0f);   // exact mul, trunc
        unsigned int rec = (unsigned int)g | (q << 15);
        int slot = atomicAdd(&cnt[s], 1);
        if (slot < CAP) bucket[s * CAP + slot] = rec;
        if (slot == 0) {                                    // unique per seq
            int bin = gene >> BIN_SHIFT;                    // genome-ordered bin
            int os  = atomicAdd(&bincnt[bin], 1);           // <=32, spread addrs
            order2D[bin * CAP2 + os] = s;                   // no overflow possible
        }
    } else {
        int idx = (b - SCATTER_BLOCKS) * 256 + threadIdx.x; // genome*32+quad
        f32x4 a  = __builtin_nontemporal_load((const f32x4*)A + idx);
        f32x4 bb = __builtin_nontemporal_load((const f32x4*)B + idx);
        __half2 h[4];
        h[0] = __floats2half2_rn(a.x + 1.0f, a.y + 1.0f);   // fold the +1 here
        h[1] = __floats2half2_rn(a.z + 1.0f, a.w + 1.0f);
        h[2] = __floats2half2_rn(bb.x, bb.y);
        h[3] = __floats2half2_rn(bb.z, bb.w);
        AB16[idx] = *reinterpret_cast<float4*>(h);          // cached: accum re-reads
    }
}

// ---------------------------------------------------------------------------
// Accum kernel, genome-ordered.
// Blocks [0, SLOT_BLOCKS): wave-slot w = global (seq-slot) index; 32 lanes per
//   slot. bin = w>>5 sweeps genomes in sorted order as blocks dispatch, so
//   concurrently-resident waves gather overlapping AB16 rows -> per-XCD L2
//   captures the ~8x genome-row reuse instead of spilling to L3 fabric.
//   Dead slots (slot >= bincnt[bin], ~2/3) exit after one broadcast load.
//   Row loads issue in parallel with cnt (bucket zero-filled -> dead record
//   slots decode to row 0, L1-hot; (j<n) mask excludes them).
// Blocks [SLOT_BLOCKS, ...): zero out[] rows of empty seqs (cnt==0, ~4k).
// ---------------------------------------------------------------------------
__global__ __launch_bounds__(256) void accum_kernel(
    const float4*       __restrict__ AB16,
    const int*          __restrict__ cnt,
    const int*          __restrict__ bincnt,
    const unsigned int* __restrict__ bucket,
    const int*          __restrict__ order2D,
    float*              __restrict__ out)
{
    int b = blockIdx.x;
    if (b >= SLOT_BLOCKS) {
        // Zero-empties path: one thread per seq.
        int seq = (b - SLOT_BLOCKS) * 256 + threadIdx.x;
        if (seq >= N_SEQS) return;
        if (cnt[seq] != 0) return;
        f32x4 z = {0.f, 0.f, 0.f, 0.f};
        f32x4* o = (f32x4*)out + (size_t)seq * 32;
        #pragma unroll
        for (int q = 0; q < 32; ++q)
            __builtin_nontemporal_store(z, o + q);
        return;
    }

    int idx  = b * 256 + threadIdx.x;
    int w    = idx >> 5;                 // wave-slot
    int quad = idx & 31;
    int bin  = w >> 5;
    int slot = w & 31;

    int m = bincnt[bin];                 // broadcast scalar
    if (slot >= m) return;               // dead slot
    int seq = order2D[bin * CAP2 + slot];

    const u32x4* bk4 = reinterpret_cast<const u32x4*>(bucket + seq * CAP);
    u32x4 r4 = bk4[0];                   // independent of cnt
    int   n  = cnt[seq];                 // in parallel with r4; n >= 1 here
    if (n > CAP) n = CAP;

    float4 acc = make_float4(0.f, 0.f, 0.f, 0.f);

    // Chunk 0 (covers n<=4, the vast majority).
    {
        unsigned int r[4] = { r4.x, r4.y, r4.z, r4.w };
        float4 raw[4];
        #pragma unroll
        for (int j = 0; j < 4; ++j)
            raw[j] = AB16[(r[j] & 0x7fffu) * 32 + quad];   // dead -> row 0 (hot)
        #pragma unroll
        for (int j = 0; j < 4; ++j) {
            float p = (float)(r[j] >> 15) * (1.0f / 131072.0f);
            const __half2* hp = reinterpret_cast<const __half2*>(&raw[j]);
            float2 a01 = __half22float2(hp[0]);
            float2 a23 = __half22float2(hp[1]);
            float2 b01 = __half22float2(hp[2]);
            float2 b23 = __half22float2(hp[3]);
            if (j < n) {
                acc.x += __expf(a01.x - p * b01.x);        // +1 folded into a
                acc.y += __expf(a01.y - p * b01.y);
                acc.z += __expf(a23.x - p * b23.x);
                acc.w += __expf(a23.y - p * b23.y);
            }
        }
    }

    // Rare tail: n > 4, chunks of 4.
    if (n > 4) {
        for (int i0 = 4; i0 < n; i0 += 4) {
            u32x4 t4 = bk4[i0 >> 2];
            unsigned int r[4] = { t4.x, t4.y, t4.z, t4.w };
            float4 raw[4];
            #pragma unroll
            for (int j = 0; j < 4; ++j)
                raw[j] = AB16[(r[j] & 0x7fffu) * 32 + quad];
            #pragma unroll
            for (int j = 0; j < 4; ++j) {
                float p = (float)(r[j] >> 15) * (1.0f / 131072.0f);
                const __half2* hp = reinterpret_cast<const __half2*>(&raw[j]);
                float2 a01 = __half22float2(hp[0]);
                float2 a23 = __half22float2(hp[1]);
                float2 b01 = __half22float2(hp[2]);
                float2 b23 = __half22float2(hp[3]);
                if (i0 + j < n) {
                    acc.x += __expf(a01.x - p * b01.x);
                    acc.y += __expf(a01.y - p * b01.y);
                    acc.z += __expf(a23.x - p * b23.x);
                    acc.w += __expf(a23.y - p * b23.y);
                }
            }
        }
    }

    f32x4 o = { acc.x, acc.y, acc.z, acc.w };
    __builtin_nontemporal_store(o, (f32x4*)out + (size_t)seq * 32 + quad);
}

extern "C" void kernel_launch(void* const* d_in, const int* in_sizes, int n_in,
                              void* d_out, int out_size, void* d_ws, size_t ws_size,
                              hipStream_t stream) {
    const float* A    = (const float*)d_in[0];
    const float* B    = (const float*)d_in[1];
    const float* pos  = (const float*)d_in[2];
    const int*   gidx = (const int*)d_in[3];
    const int*   sidx = (const int*)d_in[4];
    float*       out  = (float*)d_out;

    // Workspace layout (bytes; 256 MiB available, ~27 MB used):
    //   [0,          15,360,000)  AB16: 960000 float4 (16B-aligned)
    //   [15,360,000, 15,680,000)  cnt:     N_SEQS ints
    //   [15,680,000, 15,710,000)  bincnt:  NBIN2 ints
    //   [15,710,000, 25,950,000)  bucket:  N_SEQS*CAP uints (16B-aligned)
    //   [25,950,000, 26,910,000)  order2D: NBIN2*CAP2 ints
    char*         ws      = (char*)d_ws;
    float4*       AB16    = (float4*)ws;
    int*          cnt     = (int*)(ws + (size_t)N_GENOMES * 32 * 16);
    int*          bincnt  = cnt + N_SEQS;
    unsigned int* bucket  = (unsigned int*)(bincnt + NBIN2);
    int*          order2D = (int*)(bucket + (size_t)N_SEQS * CAP);

    // Zero cnt + bincnt + bucket in one contiguous memset (10.59 MB).
    // order2D needs no zeroing: only entries below bincnt[bin] are read.
    hipMemsetAsync(cnt, 0,
                   (size_t)(N_SEQS + NBIN2 + N_SEQS * CAP) * sizeof(int), stream);

    prep_kernel<<<SCATTER_BLOCKS + COMPRESS_BLOCKS, 256, 0, stream>>>(
        A, B, pos, gidx, sidx, cnt, bincnt, bucket, order2D, AB16);

    accum_kernel<<<SLOT_BLOCKS + EMPTY_BLOCKS, 256, 0, stream>>>(
        AB16, cnt, bincnt, bucket, order2D, out);
}

// Round 9
// 125.737 us; speedup vs baseline: 1.2456x; 1.2456x over previous
//
#include <hip/hip_runtime.h>
#include <hip/hip_fp16.h>

// Problem constants (from reference).
#define N_GENOMES 30000
#define N_GENES   240000
#define N_SAMPLES 128
#define N_SEQS    80000
#define CAP       32   // max genes per seq (Poisson mean 3; P(overflow) ~ 3e-17)

#define SCATTER_BLOCKS  ((N_GENES + 255) / 256)        // 938
#define COMPRESS_BLOCKS ((N_GENOMES * 32) / 256)       // 3750 (exact)

// Native vector types for __builtin_nontemporal_load/store.
typedef float        f32x4 __attribute__((ext_vector_type(4)));
typedef unsigned int u32x4 __attribute__((ext_vector_type(4)));

#define LOG2E 1.4426950408889634f

#if __has_builtin(__builtin_amdgcn_exp2f)
#define EXP2F(x) __builtin_amdgcn_exp2f(x)
#else
#define EXP2F(x) exp2f(x)
#endif

// ---------------------------------------------------------------------------
// Fused prep kernel.
// Blocks [0, SCATTER_BLOCKS): bucket-scatter genes by seq id with PACKED 4B
//   records: genome (15 bits) | pos quantized to 17 bits (pos*131072 exact in
//   fp32; truncation <= 2^-17). Bucket is NOT pre-zeroed; accum masks dead
//   slots by count.
// Blocks [SCATTER_BLOCKS, ...): compress A/B to fp16 interleaved per quad,
//   with BOTH the +1 and log2(e) folded in:
//   {(a+1)*log2e x4, b*log2e x4} = 16B per (genome, quad), so accum's exp is
//   a single v_exp_f32 (exp2) with no pre-multiply. A/B are read-once ->
//   nontemporal loads; AB16 store stays cached (accum re-reads it).
// ---------------------------------------------------------------------------
__global__ __launch_bounds__(256) void prep_kernel(
    const float* __restrict__ A,
    const float* __restrict__ B,
    const float* __restrict__ pos,
    const int*   __restrict__ genome_idx,
    const int*   __restrict__ seq_idx,
    int*          __restrict__ cnt,     // N_SEQS, zeroed
    unsigned int* __restrict__ bucket,  // N_SEQS * CAP packed records (uninit)
    float4*       __restrict__ AB16)    // N_GENOMES*32 x 16B interleaved fp16
{
    int b = blockIdx.x;
    if (b < SCATTER_BLOCKS) {
        int gene = b * 256 + threadIdx.x;
        if (gene >= N_GENES) return;
        int   s = seq_idx[gene];
        int   g = genome_idx[gene];
        float p = pos[gene];
        unsigned int q   = (unsigned int)(p * 131072.0f);   // exact mul, trunc
        unsigned int rec = (unsigned int)g | (q << 15);
        int slot = atomicAdd(&cnt[s], 1);
        if (slot < CAP) bucket[s * CAP + slot] = rec;
    } else {
        int idx = (b - SCATTER_BLOCKS) * 256 + threadIdx.x; // genome*32+quad
        f32x4 a  = __builtin_nontemporal_load((const f32x4*)A + idx);
        f32x4 bb = __builtin_nontemporal_load((const f32x4*)B + idx);
        __half2 h[4];
        h[0] = __floats2half2_rn((a.x + 1.0f) * LOG2E, (a.y + 1.0f) * LOG2E);
        h[1] = __floats2half2_rn((a.z + 1.0f) * LOG2E, (a.w + 1.0f) * LOG2E);
        h[2] = __floats2half2_rn(bb.x * LOG2E, bb.y * LOG2E);
        h[3] = __floats2half2_rn(bb.z * LOG2E, bb.w * LOG2E);
        AB16[idx] = *reinterpret_cast<float4*>(h);          // cached: accum re-reads
    }
}

// ---------------------------------------------------------------------------
// Accum kernel. One thread per (seq, quad); 32 lanes = one seq; seq-ordered
// grid keeps the out-store stream sequential (round-8 lesson: reordering
// seqs scrambles the 512B out bursts and regresses).
// 2-level dependent chain: {uint4 bucket-row load || cnt load} -> clamp dead
// slots' genome to row 0 (L1-hot broadcast; no junk cold rows, no bucket
// memset needed) -> 4 AB16 row loads -> exp2 accumulate -> one NT store.
// Every out element is written (n==0 -> zeros), so no out memset needed.
// ---------------------------------------------------------------------------
__global__ __launch_bounds__(256) void accum_kernel(
    const float4*       __restrict__ AB16,
    const int*          __restrict__ cnt,
    const unsigned int* __restrict__ bucket,
    float*              __restrict__ out)
{
    int idx  = blockIdx.x * blockDim.x + threadIdx.x;
    int seq  = idx >> 5;
    int quad = idx & 31;
    if (seq >= N_SEQS) return;   // grid exact; never taken

    const u32x4* bk4 = reinterpret_cast<const u32x4*>(bucket + seq * CAP); // 16B-aligned
    u32x4 r4 = bk4[0];           // issued immediately, independent of cnt
    int   n  = cnt[seq];         // issued in parallel with r4
    if (n > CAP) n = CAP;

    float4 acc = make_float4(0.f, 0.f, 0.f, 0.f);

    // Chunk 0 (covers n<=4: the vast majority of non-empty seqs).
    {
        unsigned int r[4] = { r4.x, r4.y, r4.z, r4.w };
        float4 raw[4];
        #pragma unroll
        for (int j = 0; j < 4; ++j) {
            unsigned int g = (j < n) ? (r[j] & 0x7fffu) : 0u;  // dead -> row 0 (hot)
            raw[j] = AB16[g * 32 + quad];
        }
        #pragma unroll
        for (int j = 0; j < 4; ++j) {
            float p = (float)(r[j] >> 15) * (1.0f / 131072.0f);
            const __half2* hp = reinterpret_cast<const __half2*>(&raw[j]);
            float2 a01 = __half22float2(hp[0]);
            float2 a23 = __half22float2(hp[1]);
            float2 b01 = __half22float2(hp[2]);
            float2 b23 = __half22float2(hp[3]);
            if (j < n) {                       // (a+1) and log2e folded into AB16
                acc.x += EXP2F(a01.x - p * b01.x);
                acc.y += EXP2F(a01.y - p * b01.y);
                acc.z += EXP2F(a23.x - p * b23.x);
                acc.w += EXP2F(a23.y - p * b23.y);
            }
        }
    }

    // Rare tail: n > 4, chunks of 4.
    if (n > 4) {
        for (int i0 = 4; i0 < n; i0 += 4) {
            u32x4 t4 = bk4[i0 >> 2];
            unsigned int r[4] = { t4.x, t4.y, t4.z, t4.w };
            float4 raw[4];
            #pragma unroll
            for (int j = 0; j < 4; ++j) {
                unsigned int g = (i0 + j < n) ? (r[j] & 0x7fffu) : 0u;
                raw[j] = AB16[g * 32 + quad];
            }
            #pragma unroll
            for (int j = 0; j < 4; ++j) {
                float p = (float)(r[j] >> 15) * (1.0f / 131072.0f);
                const __half2* hp = reinterpret_cast<const __half2*>(&raw[j]);
                float2 a01 = __half22float2(hp[0]);
                float2 a23 = __half22float2(hp[1]);
                float2 b01 = __half22float2(hp[2]);
                float2 b23 = __half22float2(hp[3]);
                if (i0 + j < n) {
                    acc.x += EXP2F(a01.x - p * b01.x);
                    acc.y += EXP2F(a01.y - p * b01.y);
                    acc.z += EXP2F(a23.x - p * b23.x);
                    acc.w += EXP2F(a23.y - p * b23.y);
                }
            }
        }
    }

    // Out is written once and never re-read -> nontemporal.
    f32x4 o = { acc.x, acc.y, acc.z, acc.w };
    __builtin_nontemporal_store(o, (f32x4*)out + seq * 32 + quad);
}

extern "C" void kernel_launch(void* const* d_in, const int* in_sizes, int n_in,
                              void* d_out, int out_size, void* d_ws, size_t ws_size,
                              hipStream_t stream) {
    const float* A    = (const float*)d_in[0];
    const float* B    = (const float*)d_in[1];
    const float* pos  = (const float*)d_in[2];
    const int*   gidx = (const int*)d_in[3];
    const int*   sidx = (const int*)d_in[4];
    float*       out  = (float*)d_out;

    // Workspace layout (256 MiB available, ~26 MB used):
    //   [0, 15,360,000)            AB16: 960000 float4 (16B-aligned)
    //   [15,360,000, 15,680,000)   cnt: N_SEQS ints
    //   [15,680,000, 25,920,000)   bucket: N_SEQS*CAP uints (16B-aligned)
    char*         ws     = (char*)d_ws;
    float4*       AB16   = (float4*)ws;
    int*          cnt    = (int*)(ws + (size_t)N_GENOMES * 32 * 16);
    unsigned int* bucket = (unsigned int*)(cnt + N_SEQS);

    // Zero ONLY cnt (320 KB): bucket dead slots are masked by count in accum.
    hipMemsetAsync(cnt, 0, N_SEQS * sizeof(int), stream);

    prep_kernel<<<SCATTER_BLOCKS + COMPRESS_BLOCKS, 256, 0, stream>>>(
        A, B, pos, gidx, sidx, cnt, bucket, AB16);

    const int total = N_SEQS * 32;   // 2,560,000 threads, exact grid
    accum_kernel<<<total / 256, 256, 0, stream>>>(
        AB16, cnt, bucket, out);
}